// Round 1
// baseline (255.194 us; speedup 1.0000x reference)
//
#include <hip/hip_runtime.h>

// Winograd F(2x2,3x3): x (8,64,128,128) f32, filt (64,64,3,3) f32 -> Y (8,64,126,126) f32
// T = 63 tiles per dim. U = G g G^T (k,c,4,4) in d_ws (256 KB).

#define N_B 8
#define C_CH 64
#define K_CH 64
#define T_TILES 63
#define HW 128
#define OW 126

__global__ __launch_bounds__(256)
void filter_transform(const float* __restrict__ g, float* __restrict__ U) {
    int idx = blockIdx.x * 256 + threadIdx.x;   // k*64 + c
    if (idx >= K_CH * C_CH) return;
    const float* gp = g + idx * 9;
    float g00 = gp[0], g01 = gp[1], g02 = gp[2];
    float g10 = gp[3], g11 = gp[4], g12 = gp[5];
    float g20 = gp[6], g21 = gp[7], g22 = gp[8];
    float w[4][3];
    w[0][0] = g00;                     w[0][1] = g01;                     w[0][2] = g02;
    w[1][0] = 0.5f*(g00+g10+g20);      w[1][1] = 0.5f*(g01+g11+g21);      w[1][2] = 0.5f*(g02+g12+g22);
    w[2][0] = 0.5f*(g00-g10+g20);      w[2][1] = 0.5f*(g01-g11+g21);      w[2][2] = 0.5f*(g02-g12+g22);
    w[3][0] = g20;                     w[3][1] = g21;                     w[3][2] = g22;
    float* up = U + idx * 16;
    #pragma unroll
    for (int a = 0; a < 4; ++a) {
        up[a*4+0] = w[a][0];
        up[a*4+1] = 0.5f*(w[a][0] + w[a][1] + w[a][2]);
        up[a*4+2] = 0.5f*(w[a][0] - w[a][1] + w[a][2]);
        up[a*4+3] = w[a][2];
    }
}

// Each block: one n, one 4x4 patch of tiles (16 tiles). 256 threads.
// LDS: V[c=64][tile=16] with 20-float stride (16B aligned, 2-way bank alias = free).
__global__ __launch_bounds__(256)
void winograd_main(const float* __restrict__ x, const float* __restrict__ U,
                   float* __restrict__ Y) {
    __shared__ float Vs[C_CH * 16 * 20];   // 80 KB

    const int tid = threadIdx.x;
    const int n  = blockIdx.y;
    const int pt = blockIdx.x >> 4;
    const int pu = blockIdx.x & 15;

    // ---- Phase 1: input transform into LDS ----
    #pragma unroll
    for (int i = 0; i < 4; ++i) {
        int idx  = tid + 256 * i;        // 0..1023
        int c    = idx >> 4;
        int tile = idx & 15;
        int tt = pt * 4 + (tile >> 2);
        int uu = pu * 4 + (tile & 3);
        float* vp = &Vs[(c * 16 + tile) * 20];
        if (tt < T_TILES && uu < T_TILES) {
            const float* xp = x + (((size_t)(n * C_CH + c) * HW) + 2 * tt) * HW + 2 * uu;
            float d[4][4];
            #pragma unroll
            for (int r = 0; r < 4; ++r) {
                float2 lo = *reinterpret_cast<const float2*>(xp + r * HW);
                float2 hi = *reinterpret_cast<const float2*>(xp + r * HW + 2);
                d[r][0] = lo.x; d[r][1] = lo.y; d[r][2] = hi.x; d[r][3] = hi.y;
            }
            float w[4][4];
            #pragma unroll
            for (int j = 0; j < 4; ++j) {
                w[0][j] = d[0][j] - d[2][j];
                w[1][j] = d[1][j] + d[2][j];
                w[2][j] = d[2][j] - d[1][j];
                w[3][j] = d[1][j] - d[3][j];
            }
            #pragma unroll
            for (int a = 0; a < 4; ++a) {
                vp[a*4+0] = w[a][0] - w[a][2];
                vp[a*4+1] = w[a][1] + w[a][2];
                vp[a*4+2] = w[a][2] - w[a][1];
                vp[a*4+3] = w[a][1] - w[a][3];
            }
        } else {
            #pragma unroll
            for (int a = 0; a < 16; ++a) vp[a] = 0.0f;
        }
    }
    __syncthreads();

    // ---- Phase 2: M[k,tile,a,b] = sum_c U[k,c,a,b] * V[c,tile,a,b] ----
    const int tile = tid & 15;
    const int k0   = tid >> 4;           // 0..15; thread handles k = k0 + 16*r

    float4 acc[4][4];
    #pragma unroll
    for (int r = 0; r < 4; ++r)
        #pragma unroll
        for (int q = 0; q < 4; ++q)
            acc[r][q] = make_float4(0.f, 0.f, 0.f, 0.f);

    for (int c = 0; c < C_CH; ++c) {
        const float* vp = &Vs[(c * 16 + tile) * 20];
        float4 v0 = *reinterpret_cast<const float4*>(vp + 0);
        float4 v1 = *reinterpret_cast<const float4*>(vp + 4);
        float4 v2 = *reinterpret_cast<const float4*>(vp + 8);
        float4 v3 = *reinterpret_cast<const float4*>(vp + 12);
        #pragma unroll
        for (int r = 0; r < 4; ++r) {
            const int k = k0 + 16 * r;
            const float4* up = reinterpret_cast<const float4*>(U + ((size_t)(k * C_CH + c)) * 16);
            float4 u0 = up[0], u1 = up[1], u2 = up[2], u3 = up[3];
            acc[r][0].x += u0.x * v0.x; acc[r][0].y += u0.y * v0.y;
            acc[r][0].z += u0.z * v0.z; acc[r][0].w += u0.w * v0.w;
            acc[r][1].x += u1.x * v1.x; acc[r][1].y += u1.y * v1.y;
            acc[r][1].z += u1.z * v1.z; acc[r][1].w += u1.w * v1.w;
            acc[r][2].x += u2.x * v2.x; acc[r][2].y += u2.y * v2.y;
            acc[r][2].z += u2.z * v2.z; acc[r][2].w += u2.w * v2.w;
            acc[r][3].x += u3.x * v3.x; acc[r][3].y += u3.y * v3.y;
            acc[r][3].z += u3.z * v3.z; acc[r][3].w += u3.w * v3.w;
        }
    }

    // ---- Phase 3: output transform Yt = AT * M * AT^T, store 2x2 ----
    const int tt = pt * 4 + (tile >> 2);
    const int uu = pu * 4 + (tile & 3);
    if (tt < T_TILES && uu < T_TILES) {
        #pragma unroll
        for (int r = 0; r < 4; ++r) {
            const int k = k0 + 16 * r;
            // M rows: acc[r][a] = row a (components = b)
            float4 m0 = acc[r][0], m1 = acc[r][1], m2 = acc[r][2], m3 = acc[r][3];
            float w00 = m0.x + m1.x + m2.x;
            float w01 = m0.y + m1.y + m2.y;
            float w02 = m0.z + m1.z + m2.z;
            float w03 = m0.w + m1.w + m2.w;
            float w10 = m1.x - m2.x - m3.x;
            float w11 = m1.y - m2.y - m3.y;
            float w12 = m1.z - m2.z - m3.z;
            float w13 = m1.w - m2.w - m3.w;
            float y00 = w00 + w01 + w02;
            float y01 = w01 - w02 - w03;
            float y10 = w10 + w11 + w12;
            float y11 = w11 - w12 - w13;
            float* yp = Y + (((size_t)(n * K_CH + k) * OW) + 2 * tt) * OW + 2 * uu;
            *reinterpret_cast<float2*>(yp)      = make_float2(y00, y01);
            *reinterpret_cast<float2*>(yp + OW) = make_float2(y10, y11);
        }
    }
}

extern "C" void kernel_launch(void* const* d_in, const int* in_sizes, int n_in,
                              void* d_out, int out_size, void* d_ws, size_t ws_size,
                              hipStream_t stream) {
    const float* x    = (const float*)d_in[0];
    const float* filt = (const float*)d_in[1];
    float* Y = (float*)d_out;
    float* U = (float*)d_ws;   // 64*64*16 floats = 256 KB

    filter_transform<<<16, 256, 0, stream>>>(filt, U);

    dim3 grid(256, N_B);   // 16x16 patches, 8 batches
    winograd_main<<<grid, 256, 0, stream>>>(x, U, Y);
}